// Round 4
// baseline (914.198 us; speedup 1.0000x reference)
//
#include <hip/hip_runtime.h>
#include <hip/hip_bf16.h>
#include <math.h>

constexpr int NN = 50000;   // nodes
constexpr int NE = 800000;  // edges (without self loops)
constexpr int NH = 8;       // heads

typedef __attribute__((ext_vector_type(8))) short bf16x8;
typedef __attribute__((ext_vector_type(4))) float f32x4;

__device__ inline float b2f(unsigned short u) {
  union { unsigned int i; float f; } v;
  v.i = ((unsigned int)u) << 16;
  return v.f;
}

// ---------------------------------------------------------------------------
// degree histograms (real edges only; self-loop handled inline later)
__global__ void k_deg(const int* __restrict__ src, const int* __restrict__ dst,
                      int* __restrict__ degout, int* __restrict__ degin) {
  int i = blockIdx.x * blockDim.x + threadIdx.x;
  if (i < NE) {
    atomicAdd(&degout[src[i]], 1);
    atomicAdd(&degin[dst[i]], 1);
  }
}

__global__ void k_inv(const int* __restrict__ degin, float* __restrict__ inv) {
  int i = blockIdx.x * blockDim.x + threadIdx.x;
  if (i < NN) inv[i] = 1.0f / (float)(degin[i] + 1);
}

// single-block exclusive scan of degout -> base (also cursor = base)
__global__ void __launch_bounds__(1024) k_scan(const int* __restrict__ deg,
                                               int* __restrict__ base,
                                               int* __restrict__ cursor) {
  __shared__ int ls[1024];
  const int t = threadIdx.x;
  const int CHK = (NN + 1023) / 1024;  // 49
  const int start = t * CHK;
  int s = 0;
  for (int i = 0; i < CHK; ++i) {
    int idx = start + i;
    if (idx < NN) s += deg[idx];
  }
  ls[t] = s;
  __syncthreads();
  for (int off = 1; off < 1024; off <<= 1) {
    int v = (t >= off) ? ls[t - off] : 0;
    __syncthreads();
    ls[t] += v;
    __syncthreads();
  }
  int prefix = ls[t] - s;  // exclusive prefix for this chunk
  for (int i = 0; i < CHK; ++i) {
    int idx = start + i;
    if (idx < NN) {
      base[idx] = prefix;
      cursor[idx] = prefix;
      prefix += deg[idx];
    }
  }
}

// scatter: csr_dst grouped by src. After this, cursor[n] == end of n's range.
__global__ void k_scatter(const int* __restrict__ src, const int* __restrict__ dst,
                          int* __restrict__ cursor, int* __restrict__ csr_dst) {
  int e = blockIdx.x * blockDim.x + threadIdx.x;
  if (e < NE) {
    int pos = atomicAdd(&cursor[src[e]], 1);
    csr_dst[pos] = dst[e];
  }
}

// ---------------------------------------------------------------------------
// fp32 -> bf16 conversion, 4 elements/thread
__global__ void k_f2b(const float* __restrict__ in, __hip_bfloat16* __restrict__ out,
                      long n4) {
  long i = (long)blockIdx.x * blockDim.x + threadIdx.x;
  if (i >= n4) return;
  float4 v = reinterpret_cast<const float4*>(in)[i];
  ushort4 o;
  o.x = __hip_bfloat16_raw(__float2bfloat16(v.x)).x;
  o.y = __hip_bfloat16_raw(__float2bfloat16(v.y)).x;
  o.z = __hip_bfloat16_raw(__float2bfloat16(v.z)).x;
  o.w = __hip_bfloat16_raw(__float2bfloat16(v.w)).x;
  reinterpret_cast<ushort4*>(out)[i] = o;
}

// ---------------------------------------------------------------------------
// q[n,h] = sum_c X[n,c] * U[h,c]   (fp32, tiny)
__global__ void k_q(const float* __restrict__ X, const float* __restrict__ U,
                    float* __restrict__ q) {
  int n = blockIdx.x * blockDim.x + threadIdx.x;
  if (n >= NN) return;
  float4 xr[16];
  const float4* X4 = reinterpret_cast<const float4*>(X) + (size_t)n * 16;
#pragma unroll
  for (int i = 0; i < 16; ++i) xr[i] = X4[i];
  const float4* U4 = reinterpret_cast<const float4*>(U);
#pragma unroll
  for (int h = 0; h < 8; ++h) {
    float a = 0.f;
#pragma unroll
    for (int i = 0; i < 16; ++i) {
      float4 u = U4[h * 16 + i];
      a = fmaf(xr[i].x, u.x, a);
      a = fmaf(xr[i].y, u.y, a);
      a = fmaf(xr[i].z, u.z, a);
      a = fmaf(xr[i].w, u.w, a);
    }
    q[(size_t)n * 8 + h] = a;
  }
}

// ---------------------------------------------------------------------------
// P[n, j] = sum_c Xb[n,c] * Wb[j,c]  via MFMA bf16 (K=64 -> 2 k-steps of 32)
template <int JDIM>
__global__ void __launch_bounds__(JDIM / 64 * 64)
k_mfma_gemm(const __hip_bfloat16* __restrict__ Xb,
            const __hip_bfloat16* __restrict__ Wb,
            __hip_bfloat16* __restrict__ Pb) {
  const int lane = threadIdx.x & 63;
  const int w = threadIdx.x >> 6;  // wave id -> n tile
  const int m0 = blockIdx.x * 64;
  const int n0 = w * 64;
  const int lr = lane & 15;
  const int lk = lane >> 4;

  const ushort* X = reinterpret_cast<const ushort*>(Xb);
  const ushort* W = reinterpret_cast<const ushort*>(Wb);

  bf16x8 bfr[4][2];
#pragma unroll
  for (int ni = 0; ni < 4; ++ni)
#pragma unroll
    for (int kk = 0; kk < 2; ++kk) {
      int j = n0 + ni * 16 + lr;
      bfr[ni][kk] = *reinterpret_cast<const bf16x8*>(W + (size_t)j * 64 + kk * 32 + lk * 8);
    }

  bf16x8 afr[4][2];
#pragma unroll
  for (int mi = 0; mi < 4; ++mi)
#pragma unroll
    for (int kk = 0; kk < 2; ++kk) {
      int r = m0 + mi * 16 + lr;
      if (r >= NN) r = NN - 1;  // clamp; results discarded by store guard
      afr[mi][kk] = *reinterpret_cast<const bf16x8*>(X + (size_t)r * 64 + kk * 32 + lk * 8);
    }

  f32x4 acc[4][4] = {};
#pragma unroll
  for (int mi = 0; mi < 4; ++mi)
#pragma unroll
    for (int ni = 0; ni < 4; ++ni)
#pragma unroll
      for (int kk = 0; kk < 2; ++kk)
        acc[mi][ni] = __builtin_amdgcn_mfma_f32_16x16x32_bf16(
            afr[mi][kk], bfr[ni][kk], acc[mi][ni], 0, 0, 0);

#pragma unroll
  for (int mi = 0; mi < 4; ++mi) {
#pragma unroll
    for (int i = 0; i < 4; ++i) {
      int r = m0 + mi * 16 + lk * 4 + i;
      if (r < NN) {
#pragma unroll
        for (int ni = 0; ni < 4; ++ni) {
          int j = n0 + ni * 16 + lr;
          Pb[(size_t)r * JDIM + j] = __float2bfloat16(acc[mi][ni][i]);
        }
      }
    }
  }
}

// ---------------------------------------------------------------------------
// src-major edge kernel: one node per wave (COUT=64) / two per wave (COUT=32).
// Lane o keeps P[src][h*COUT+o] in registers; loop over out-edges:
// q[dst] load, softmax, 8 reg FMAs, one atomic scatter per edge.
// Self-loop handled inline (logits == c exactly, since q_d - q_s == 0).
// NOTE: readfirstlane is ONLY legal when NPW==1 (whole wave shares the node);
// for NPW==2 the two half-waves have different dst streams (round-3 bug).
template <int COUT>
__global__ void k_edge_csr(const int* __restrict__ base, const int* __restrict__ endp,
                           const int* __restrict__ csr_dst,
                           const float* __restrict__ q, const float* __restrict__ cvec,
                           const __hip_bfloat16* __restrict__ Pb,
                           float* __restrict__ agg) {
  constexpr int NPW = 64 / COUT;  // nodes per wave
  const int lane = threadIdx.x & 63;
  const long wid = ((long)blockIdx.x * blockDim.x + threadIdx.x) >> 6;
  const int n = (int)(wid * NPW + (NPW == 1 ? 0 : (lane >> 5)));
  if (n >= NN) return;
  const int o = lane & (COUT - 1);

  // P row fragment -> registers (one-time, coalesced 128B segments)
  const ushort* P = reinterpret_cast<const ushort*>(Pb);
  float p[NH];
#pragma unroll
  for (int h = 0; h < NH; ++h) p[h] = b2f(P[(size_t)n * (NH * COUT) + h * COUT + o]);

  const float4* q4 = reinterpret_cast<const float4*>(q);
  const float4* c4 = reinterpret_cast<const float4*>(cvec);
  float4 qs0 = q4[2 * n], qs1 = q4[2 * n + 1];
  float4 c0 = c4[0], c1 = c4[1];

  float t[8];
  t[0] = c0.x - qs0.x;  t[1] = c0.y - qs0.y;  t[2] = c0.z - qs0.z;  t[3] = c0.w - qs0.w;
  t[4] = c1.x - qs1.x;  t[5] = c1.y - qs1.y;  t[6] = c1.z - qs1.z;  t[7] = c1.w - qs1.w;

  // ---- self-loop: logits = c exactly ----
  {
    float l[8] = {c0.x, c0.y, c0.z, c0.w, c1.x, c1.y, c1.z, c1.w};
    float m = l[0];
#pragma unroll
    for (int h = 1; h < 8; ++h) m = fmaxf(m, l[h]);
    float sum = 0.f, acc = 0.f;
#pragma unroll
    for (int h = 0; h < 8; ++h) {
      float e = __expf(l[h] - m);
      sum += e;
      acc = fmaf(e, p[h], acc);
    }
    atomicAdd(&agg[(size_t)n * COUT + o], acc / sum);
  }

  // ---- out-edges ----
  for (int k = base[n], k1 = endp[n]; k < k1; ++k) {
    int d = csr_dst[k];
    if constexpr (NPW == 1) d = __builtin_amdgcn_readfirstlane(d);
    float4 qd0 = q4[2 * d], qd1 = q4[2 * d + 1];
    float l[8];
    l[0] = qd0.x + t[0];  l[1] = qd0.y + t[1];
    l[2] = qd0.z + t[2];  l[3] = qd0.w + t[3];
    l[4] = qd1.x + t[4];  l[5] = qd1.y + t[5];
    l[6] = qd1.z + t[6];  l[7] = qd1.w + t[7];
    float m = l[0];
#pragma unroll
    for (int h = 1; h < 8; ++h) m = fmaxf(m, l[h]);
    float sum = 0.f, acc = 0.f;
#pragma unroll
    for (int h = 0; h < 8; ++h) {
      float e = __expf(l[h] - m);
      sum += e;
      acc = fmaf(e, p[h], acc);
    }
    atomicAdd(&agg[(size_t)d * COUT + o], acc / sum);
  }
}

// ---------------------------------------------------------------------------
// y = relu(agg*inv + b); accumulate per-channel sum/sumsq into stats
__global__ void k_finalize_relu(const float* __restrict__ agg, const float* __restrict__ inv,
                                const float* __restrict__ b, float* __restrict__ y,
                                float* __restrict__ stats) {
  __shared__ float ssum[64], ssq[64];
  const int t = threadIdx.x;
  if (t < 64) { ssum[t] = 0.f; ssq[t] = 0.f; }
  __syncthreads();

  const int o = t & 63;
  const float bo = b[o];
  float lsum = 0.f, lsq = 0.f;
  for (long idx = (long)blockIdx.x * blockDim.x + threadIdx.x; idx < (long)NN * 64;
       idx += (long)gridDim.x * blockDim.x) {
    int n = (int)(idx >> 6);
    float v = fmaf(agg[idx], inv[n], bo);
    v = fmaxf(v, 0.f);
    y[idx] = v;
    lsum += v;
    lsq = fmaf(v, v, lsq);
  }
  atomicAdd(&ssum[o], lsum);
  atomicAdd(&ssq[o], lsq);
  __syncthreads();
  if (t < 64) {
    atomicAdd(&stats[t], ssum[t]);
    atomicAdd(&stats[64 + t], ssq[t]);
  }
}

// BN: writes h (fp32, for next layer's q) and hb (bf16, for MFMA)
__global__ void k_bn(const float* __restrict__ y, const float* __restrict__ stats,
                     const float* __restrict__ g, const float* __restrict__ be,
                     float* __restrict__ h, __hip_bfloat16* __restrict__ hb) {
  long idx = (long)blockIdx.x * blockDim.x + threadIdx.x;
  if (idx >= (long)NN * 64) return;
  int o = (int)(idx & 63);
  float m = stats[o] * (1.0f / NN);
  float v = stats[64 + o] * (1.0f / NN) - m * m;
  float r = fmaf(g[o] * rsqrtf(v + 1e-5f), y[idx] - m, be[o]);
  h[idx] = r;
  hb[idx] = __float2bfloat16(r);
}

__global__ void k_final(const float* __restrict__ agg, const float* __restrict__ inv,
                        const float* __restrict__ b, float* __restrict__ out) {
  long idx = (long)blockIdx.x * blockDim.x + threadIdx.x;
  if (idx >= (long)NN * 32) return;
  int n = (int)(idx >> 5);
  int o = (int)(idx & 31);
  out[idx] = fmaf(agg[idx], inv[n], b[o]);
}

// ---------------------------------------------------------------------------
extern "C" void kernel_launch(void* const* d_in, const int* in_sizes, int n_in,
                              void* d_out, int out_size, void* d_ws, size_t ws_size,
                              hipStream_t stream) {
  const float* x   = (const float*)d_in[0];
  const int*   src = (const int*)d_in[1];
  const int*   dst = src + NE;
  const float* W1 = (const float*)d_in[2];
  const float* U1 = (const float*)d_in[3];
  const float* c1 = (const float*)d_in[4];
  const float* b1 = (const float*)d_in[5];
  const float* g1 = (const float*)d_in[6];
  const float* be1 = (const float*)d_in[7];
  const float* W2 = (const float*)d_in[8];
  const float* U2 = (const float*)d_in[9];
  const float* c2 = (const float*)d_in[10];
  const float* b2 = (const float*)d_in[11];
  const float* g2 = (const float*)d_in[12];
  const float* be2 = (const float*)d_in[13];
  const float* W3 = (const float*)d_in[14];
  const float* U3 = (const float*)d_in[15];
  const float* c3 = (const float*)d_in[16];
  const float* b3 = (const float*)d_in[17];
  float* out = (float*)d_out;

  // workspace layout (float-equivalents)
  float* ws   = (float*)d_ws;
  float* inv  = ws;                        // N
  float* q    = inv + NN;                  // N*8
  float* agg  = q + (size_t)NN * 8;        // N*64
  float* h    = agg + (size_t)NN * 64;     // N*64
  float* stats = h + (size_t)NN * 64;      // 128
  __hip_bfloat16* xb = (__hip_bfloat16*)(stats + 128);           // N*64 bf16
  __hip_bfloat16* Wb = xb + (size_t)NN * 64;                     // 512*64 bf16
  __hip_bfloat16* Pb = Wb + 512 * 64;                            // N*512 bf16
  int* degout  = (int*)(Pb + (size_t)NN * 512);                  // N
  int* degin   = degout + NN;                                    // N
  int* basep   = degin + NN;                                     // N
  int* cursor  = basep + NN;                                     // N
  int* csr_dst = cursor + NN;                                    // NE

  const int BLK = 256;
  dim3 b256(BLK);

  // ---- CSR build (once; reused by all 3 layers) ----
  hipMemsetAsync(degout, 0, (size_t)NN * 8, stream);  // degout + degin
  k_deg<<<dim3((NE + BLK - 1) / BLK), b256, 0, stream>>>(src, dst, degout, degin);
  k_inv<<<dim3((NN + BLK - 1) / BLK), b256, 0, stream>>>(degin, inv);
  k_scan<<<dim3(1), dim3(1024), 0, stream>>>(degout, basep, cursor);
  k_scatter<<<dim3((NE + BLK - 1) / BLK), b256, 0, stream>>>(src, dst, cursor, csr_dst);

  const int qgrid = (NN + BLK - 1) / BLK;
  const int mfma_grid = (NN + 63) / 64;
  const int csr_grid64 = (NN * 64 + BLK - 1) / BLK;       // 1 node per wave
  const int csr_grid32 = (NN * 32 + BLK - 1) / BLK;       // 2 nodes per wave
  const long xb4 = (long)NN * 64 / 4;
  const long wb4_512 = 512 * 64 / 4;

  // ---- layer 1: x -> h ----
  k_f2b<<<dim3((xb4 + BLK - 1) / BLK), b256, 0, stream>>>(x, xb, xb4);
  k_f2b<<<dim3((wb4_512 + BLK - 1) / BLK), b256, 0, stream>>>(W1, Wb, wb4_512);
  k_q<<<dim3(qgrid), b256, 0, stream>>>(x, U1, q);
  k_mfma_gemm<512><<<dim3(mfma_grid), dim3(512), 0, stream>>>(xb, Wb, Pb);
  hipMemsetAsync(agg, 0, (size_t)NN * 64 * 4, stream);
  hipMemsetAsync(stats, 0, 128 * 4, stream);
  k_edge_csr<64><<<dim3(csr_grid64), b256, 0, stream>>>(basep, cursor, csr_dst, q, c1, Pb, agg);
  k_finalize_relu<<<dim3(1024), b256, 0, stream>>>(agg, inv, b1, h, stats);
  k_bn<<<dim3(((size_t)NN * 64 + BLK - 1) / BLK), b256, 0, stream>>>(h, stats, g1, be1, h, xb);

  // ---- layer 2: h -> h ----
  k_f2b<<<dim3((wb4_512 + BLK - 1) / BLK), b256, 0, stream>>>(W2, Wb, wb4_512);
  k_q<<<dim3(qgrid), b256, 0, stream>>>(h, U2, q);
  k_mfma_gemm<512><<<dim3(mfma_grid), dim3(512), 0, stream>>>(xb, Wb, Pb);
  hipMemsetAsync(agg, 0, (size_t)NN * 64 * 4, stream);
  hipMemsetAsync(stats, 0, 128 * 4, stream);
  k_edge_csr<64><<<dim3(csr_grid64), b256, 0, stream>>>(basep, cursor, csr_dst, q, c2, Pb, agg);
  k_finalize_relu<<<dim3(1024), b256, 0, stream>>>(agg, inv, b2, h, stats);
  k_bn<<<dim3(((size_t)NN * 64 + BLK - 1) / BLK), b256, 0, stream>>>(h, stats, g2, be2, h, xb);

  // ---- layer 3: h -> out ----
  const long wb4_256 = 256 * 64 / 4;
  k_f2b<<<dim3((wb4_256 + BLK - 1) / BLK), b256, 0, stream>>>(W3, Wb, wb4_256);
  k_q<<<dim3(qgrid), b256, 0, stream>>>(h, U3, q);
  k_mfma_gemm<256><<<dim3(mfma_grid), dim3(256), 0, stream>>>(xb, Wb, Pb);
  hipMemsetAsync(agg, 0, (size_t)NN * 32 * 4, stream);
  k_edge_csr<32><<<dim3(csr_grid32), b256, 0, stream>>>(basep, cursor, csr_dst, q, c3, Pb, agg);
  k_final<<<dim3(((size_t)NN * 32 + BLK - 1) / BLK), b256, 0, stream>>>(agg, inv, b3, out);
}